// Round 1
// baseline (1035.960 us; speedup 1.0000x reference)
//
#include <hip/hip_runtime.h>
#include <hip/hip_bf16.h>

#define WID 32
#define KER 6
#define DEPTH 4
#define WEXT_ELEMS (33 * 2 * 64 * 8)   // steps x ntiles x lanes x 8

typedef __attribute__((ext_vector_type(8))) short bf16x8;
typedef __attribute__((ext_vector_type(4))) float f32x4;

static __device__ __forceinline__ float bf2f(unsigned short u) {
  union { unsigned int u; float f; } v; v.u = ((unsigned int)u) << 16; return v.f;
}
static __device__ __forceinline__ unsigned short f2bf(float f) {
  union { float f; unsigned int u; } v; v.f = f;
  unsigned int r = v.u + 0x7fffu + ((v.u >> 16) & 1u);
  return (unsigned short)(r >> 16);
}

// ---------------- h0 = x @ fc1_w + fc1_b (N,1)@(1,32) -----------------
__global__ void k_h0(const float* __restrict__ x, const float* __restrict__ w,
                     const float* __restrict__ b, float* __restrict__ h,
                     unsigned short* __restrict__ hbf, int n_nodes) {
  int gid = blockIdx.x * blockDim.x + threadIdx.x;
  if (gid >= n_nodes * WID) return;
  int n = gid >> 5, o = gid & 31;
  float v = x[n] * w[o] + b[o];
  h[gid] = v;
  hbf[gid] = f2bf(v);
}

// ---------------- edge MLP: ea(6) -> 8 -> 32, ReLU both, store bf16 ----
__global__ void k_edgemlp(const float* __restrict__ ea,
                          const float* __restrict__ w1, const float* __restrict__ b1,
                          const float* __restrict__ w2, const float* __restrict__ b2,
                          unsigned short* __restrict__ h3, int ecnt) {
  __shared__ float sw1[KER * 8], sb1[8], sw2[8 * WID], sb2[WID];
  int tid = threadIdx.x;
  if (tid < KER * 8) sw1[tid] = w1[tid];
  if (tid < 8) sb1[tid] = b1[tid];
  if (tid < 8 * WID) sw2[tid] = w2[tid];
  if (tid < WID) sb2[tid] = b2[tid];
  __syncthreads();
  int e = blockIdx.x * blockDim.x + tid;
  if (e >= ecnt) return;
  float a[KER];
  #pragma unroll
  for (int i = 0; i < KER; i++) a[i] = ea[e * KER + i];
  float h8[8];
  #pragma unroll
  for (int o = 0; o < 8; o++) {
    float s = sb1[o];
    #pragma unroll
    for (int i = 0; i < KER; i++) s += a[i] * sw1[i * 8 + o];
    h8[o] = fmaxf(s, 0.f);
  }
  #pragma unroll
  for (int o = 0; o < WID; o++) {
    float s = sb2[o];
    #pragma unroll
    for (int i = 0; i < 8; i++) s += h8[i] * sw2[i * WID + o];
    h3[e * WID + o] = f2bf(fmaxf(s, 0.f));
  }
}

// ---------------- in-degree counts ------------------------------------
__global__ void k_cnt(const int* __restrict__ dst, int ecnt, unsigned int* __restrict__ cnt) {
  int e = blockIdx.x * blockDim.x + threadIdx.x;
  if (e < ecnt) atomicAdd(&cnt[dst[e]], 1u);
}

// ---- pack Wext (w3 rows reindexed kk = kh*32 + i, plus b3 rows) into
// ---- exact B-fragment order: [step s][ntile t][lane l][j], bf16 ------
__global__ void k_pack(const float* __restrict__ w3, const float* __restrict__ b3,
                       unsigned short* __restrict__ outp) {
  int idx = blockIdx.x * blockDim.x + threadIdx.x;
  if (idx >= WEXT_ELEMS) return;
  int j = idx & 7, l = (idx >> 3) & 63, tt = (idx >> 9) & 1, s = idx >> 10;
  int p = ((l >> 4) << 3) + j;        // within-step K position = i (h index)
  int o = tt * 16 + (l & 15);         // output channel
  // row kk = s*32 + p ; for s<32: kh=s, i=p -> w3[kh][i*32+o] ; s==32: b3 rows
  float v = (s < 32) ? w3[s * 1024 + p * 32 + o] : b3[p * 32 + o];
  outp[idx] = f2bf(v);
}

// ---------------- message kernel: per wave, 16 edges, MFMA ------------
// z[e, kk=kh*32+i] = h_src[e][i]*h3[e][kh]; msg = [z ; h_src] @ [Wf ; B3]
__launch_bounds__(512, 4)
__global__ void k_msg(const unsigned short* __restrict__ hbf,
                      const unsigned short* __restrict__ h3,
                      const int* __restrict__ eidx, int ecnt,
                      const unsigned short* __restrict__ wext,
                      float* __restrict__ agg) {
  __shared__ __align__(16) unsigned short wlds[WEXT_ELEMS];   // 67584 B
  {
    const uint4* s4 = (const uint4*)wext;
    uint4* d4 = (uint4*)wlds;
    for (int i = threadIdx.x; i < WEXT_ELEMS / 8; i += blockDim.x) d4[i] = s4[i];
  }
  __syncthreads();
  const int lane = threadIdx.x & 63;
  const int wv = threadIdx.x >> 6;
  const int g = lane >> 4, eo = lane & 15;
  const int ntile = ecnt >> 4;
  const int wpb = blockDim.x >> 6;
  const int nwv = gridDim.x * wpb;
  for (int tile = blockIdx.x * wpb + wv; tile < ntile; tile += nwv) {
    const int e = (tile << 4) + eo;
    const int srcn = eidx[e];
    // full h3 row (32 bf16) for this lane's edge
    const uint4* h3p = (const uint4*)(h3 + (size_t)e * WID);
    uint4 q0 = h3p[0], q1 = h3p[1], q2 = h3p[2], q3 = h3p[3];
    unsigned int h3w[16];
    h3w[0]=q0.x; h3w[1]=q0.y; h3w[2]=q0.z; h3w[3]=q0.w;
    h3w[4]=q1.x; h3w[5]=q1.y; h3w[6]=q1.z; h3w[7]=q1.w;
    h3w[8]=q2.x; h3w[9]=q2.y; h3w[10]=q2.z; h3w[11]=q2.w;
    h3w[12]=q3.x; h3w[13]=q3.y; h3w[14]=q3.z; h3w[15]=q3.w;
    // h_src fragment: 8 bf16 at positions g*8..g*8+7
    uint4 hq = *(const uint4*)(hbf + (size_t)srcn * WID + g * 8);
    bf16x8 hsv = __builtin_bit_cast(bf16x8, hq);
    float hsf[8];
    #pragma unroll
    for (int j = 0; j < 8; j++) hsf[j] = bf2f((unsigned short)hsv[j]);
    f32x4 acc0 = {0.f, 0.f, 0.f, 0.f};
    f32x4 acc1 = {0.f, 0.f, 0.f, 0.f};
    #pragma unroll
    for (int s = 0; s < 32; s++) {
      unsigned int wrd = h3w[s >> 1];
      unsigned short h3b = (s & 1) ? (unsigned short)(wrd >> 16) : (unsigned short)(wrd & 0xffffu);
      float h3s = bf2f(h3b);
      bf16x8 af;
      #pragma unroll
      for (int j = 0; j < 8; j++) af[j] = (short)f2bf(h3s * hsf[j]);
      bf16x8 b0 = *(const bf16x8*)&wlds[((s * 2 + 0) * 64 + lane) * 8];
      bf16x8 b1 = *(const bf16x8*)&wlds[((s * 2 + 1) * 64 + lane) * 8];
      acc0 = __builtin_amdgcn_mfma_f32_16x16x32_bf16(af, b0, acc0, 0, 0, 0);
      acc1 = __builtin_amdgcn_mfma_f32_16x16x32_bf16(af, b1, acc1, 0, 0, 0);
    }
    { // step 32: bias rows, A = raw h_src fragment
      bf16x8 b0 = *(const bf16x8*)&wlds[((32 * 2 + 0) * 64 + lane) * 8];
      bf16x8 b1 = *(const bf16x8*)&wlds[((32 * 2 + 1) * 64 + lane) * 8];
      acc0 = __builtin_amdgcn_mfma_f32_16x16x32_bf16(hsv, b0, acc0, 0, 0, 0);
      acc1 = __builtin_amdgcn_mfma_f32_16x16x32_bf16(hsv, b1, acc1, 0, 0, 0);
    }
    // D layout (measured m89): col = lane&15 (channel), row = (lane>>4)*4+r (edge)
    #pragma unroll
    for (int r = 0; r < 4; r++) {
      int oe = (tile << 4) + g * 4 + r;
      int d = eidx[ecnt + oe];       // dst row of edge_index
      atomicAdd(&agg[d * WID + eo], acc0[r]);
      atomicAdd(&agg[d * WID + 16 + eo], acc1[r]);
    }
  }
}

// ---------------- node update: mean1+mean2 + h@(root1+root2)+bias, ReLU
__global__ void k_update(const float* __restrict__ agg1, const float* __restrict__ agg2,
                         const unsigned int* __restrict__ cnt1, const unsigned int* __restrict__ cnt2,
                         const float* __restrict__ root1, const float* __restrict__ root2,
                         const float* __restrict__ bias1, const float* __restrict__ bias2,
                         float* __restrict__ h, unsigned short* __restrict__ hbf,
                         int last, const float* __restrict__ fc2w, const float* __restrict__ fc2b,
                         float* __restrict__ out, int n_nodes) {
  __shared__ float rs[WID * WID];
  __shared__ float bs[WID];
  __shared__ float hrow[8][WID];
  int tid = threadIdx.x;
  for (int i = tid; i < WID * WID; i += blockDim.x) rs[i] = root1[i] + root2[i];
  if (tid < WID) bs[tid] = bias1[tid] + bias2[tid];
  int o = tid & 31, nl = tid >> 5;
  int n = blockIdx.x * 8 + nl;
  bool ok = (n < n_nodes);
  hrow[nl][o] = ok ? h[n * WID + o] : 0.f;
  __syncthreads();
  if (!ok) return;
  float c1 = cnt1[n] ? (float)cnt1[n] : 1.f;
  float c2 = cnt2[n] ? (float)cnt2[n] : 1.f;
  float v = agg1[n * WID + o] / c1 + agg2[n * WID + o] / c2 + bs[o];
  #pragma unroll
  for (int i = 0; i < WID; i++) v += hrow[nl][i] * rs[i * WID + o];
  v = fmaxf(v, 0.f);
  h[n * WID + o] = v;
  hbf[n * WID + o] = f2bf(v);
  if (last) {
    float pv = v * fc2w[o];
    #pragma unroll
    for (int m = 16; m >= 1; m >>= 1) pv += __shfl_xor(pv, m, 32);
    if (o == 0) out[n] = pv + fc2b[0];
  }
}

extern "C" void kernel_launch(void* const* d_in, const int* in_sizes, int n_in,
                              void* d_out, int out_size, void* d_ws, size_t ws_size,
                              hipStream_t stream) {
  const float* x    = (const float*)d_in[0];
  const int*   ei   = (const int*)d_in[1];
  const float* ea   = (const float*)d_in[2];
  const int*   eib  = (const int*)d_in[3];
  const float* eab  = (const float*)d_in[4];
  const float* fc1w = (const float*)d_in[5];
  const float* fc1b = (const float*)d_in[6];
  const float* k1w1 = (const float*)d_in[7];
  const float* k1b1 = (const float*)d_in[8];
  const float* k1w2 = (const float*)d_in[9];
  const float* k1b2 = (const float*)d_in[10];
  const float* k1w3 = (const float*)d_in[11];
  const float* k1b3 = (const float*)d_in[12];
  const float* k2w1 = (const float*)d_in[13];
  const float* k2b1 = (const float*)d_in[14];
  const float* k2w2 = (const float*)d_in[15];
  const float* k2b2 = (const float*)d_in[16];
  const float* k2w3 = (const float*)d_in[17];
  const float* k2b3 = (const float*)d_in[18];
  const float* root1 = (const float*)d_in[19];
  const float* bias1 = (const float*)d_in[20];
  const float* root2 = (const float*)d_in[21];
  const float* bias2 = (const float*)d_in[22];
  const float* fc2w = (const float*)d_in[23];
  const float* fc2b = (const float*)d_in[24];
  float* out = (float*)d_out;

  const int n_nodes = in_sizes[0];
  const int E  = in_sizes[1] / 2;
  const int EB = in_sizes[3] / 2;

  char* ws = (char*)d_ws;
  size_t off = 0;
  auto alloc = [&](size_t bytes) -> void* {
    void* p = ws + off;
    off = (off + bytes + 255) & ~(size_t)255;
    return p;
  };
  unsigned short* h3_1 = (unsigned short*)alloc((size_t)E * WID * 2);
  unsigned short* h3_2 = (unsigned short*)alloc((size_t)EB * WID * 2);
  unsigned short* w1b  = (unsigned short*)alloc((size_t)WEXT_ELEMS * 2);
  unsigned short* w2b  = (unsigned short*)alloc((size_t)WEXT_ELEMS * 2);
  float* h             = (float*)alloc((size_t)n_nodes * WID * 4);
  unsigned short* hbf  = (unsigned short*)alloc((size_t)n_nodes * WID * 2);
  float* agg1          = (float*)alloc((size_t)n_nodes * WID * 4);
  float* agg2          = (float*)alloc((size_t)n_nodes * WID * 4);
  unsigned int* cnt1   = (unsigned int*)alloc((size_t)n_nodes * 4);
  unsigned int* cnt2   = (unsigned int*)alloc((size_t)n_nodes * 4);
  (void)ws_size; (void)n_in; (void)out_size;

  hipMemsetAsync(cnt1, 0, (size_t)n_nodes * 4, stream);
  hipMemsetAsync(cnt2, 0, (size_t)n_nodes * 4, stream);
  k_cnt<<<(E + 255) / 256, 256, 0, stream>>>(ei + E, E, cnt1);
  k_cnt<<<(EB + 255) / 256, 256, 0, stream>>>(eib + EB, EB, cnt2);
  k_h0<<<(n_nodes * WID + 255) / 256, 256, 0, stream>>>(x, fc1w, fc1b, h, hbf, n_nodes);
  k_edgemlp<<<(E + 255) / 256, 256, 0, stream>>>(ea, k1w1, k1b1, k1w2, k1b2, h3_1, E);
  k_edgemlp<<<(EB + 255) / 256, 256, 0, stream>>>(eab, k2w1, k2b1, k2w2, k2b2, h3_2, EB);
  k_pack<<<(WEXT_ELEMS + 255) / 256, 256, 0, stream>>>(k1w3, k1b3, w1b);
  k_pack<<<(WEXT_ELEMS + 255) / 256, 256, 0, stream>>>(k2w3, k2b3, w2b);

  for (int t = 0; t < DEPTH; t++) {
    hipMemsetAsync(agg1, 0, (size_t)n_nodes * WID * 4, stream);
    hipMemsetAsync(agg2, 0, (size_t)n_nodes * WID * 4, stream);
    k_msg<<<256, 512, 0, stream>>>(hbf, h3_1, ei, E, w1b, agg1);
    k_msg<<<256, 512, 0, stream>>>(hbf, h3_2, eib, EB, w2b, agg2);
    int last = (t == DEPTH - 1);
    k_update<<<(n_nodes + 7) / 8, 256, 0, stream>>>(agg1, agg2, cnt1, cnt2, root1, root2,
                                                    bias1, bias2, h, hbf, last, fc2w, fc2b,
                                                    out, n_nodes);
  }
}

// Round 3
// 681.664 us; speedup vs baseline: 1.5198x; 1.5198x over previous
//
#include <hip/hip_runtime.h>
#include <hip/hip_bf16.h>

#define WID 32
#define KER 6
#define DEPTH 4
#define WEXT_ELEMS (33 * 2 * 64 * 8)   // steps x ntiles x lanes x 8

typedef __attribute__((ext_vector_type(8))) short bf16x8;
typedef __attribute__((ext_vector_type(4))) float f32x4;

static __device__ __forceinline__ float bf2f(unsigned short u) {
  union { unsigned int u; float f; } v; v.u = ((unsigned int)u) << 16; return v.f;
}
static __device__ __forceinline__ unsigned short f2bf(float f) {
  union { float f; unsigned int u; } v; v.f = f;
  unsigned int r = v.u + 0x7fffu + ((v.u >> 16) & 1u);
  return (unsigned short)(r >> 16);
}

// ---------------- h0 = x @ fc1_w + fc1_b (N,1)@(1,32) -----------------
__global__ void k_h0(const float* __restrict__ x, const float* __restrict__ w,
                     const float* __restrict__ b, float* __restrict__ h,
                     unsigned short* __restrict__ hbf, int n_nodes) {
  int gid = blockIdx.x * blockDim.x + threadIdx.x;
  if (gid >= n_nodes * WID) return;
  int n = gid >> 5, o = gid & 31;
  float v = x[n] * w[o] + b[o];
  h[gid] = v;
  hbf[gid] = f2bf(v);
}

// ---------------- degree histogram (both edge sets, one dispatch) -----
__global__ void k_cnt(const int* __restrict__ ei, int E,
                      const int* __restrict__ eib, int EB,
                      unsigned int* __restrict__ cnt1, unsigned int* __restrict__ cnt2) {
  int idx = blockIdx.x * blockDim.x + threadIdx.x;
  if (idx < E) {
    atomicAdd(&cnt1[ei[E + idx]], 1u);
  } else if (idx < E + EB) {
    atomicAdd(&cnt2[eib[EB + (idx - E)]], 1u);
  }
}

// ---------------- exclusive scan, one block per array -----------------
__global__ void k_scan(const unsigned int* __restrict__ cnt1, unsigned int* __restrict__ start1,
                       const unsigned int* __restrict__ cnt2, unsigned int* __restrict__ start2,
                       int n) {
  const unsigned int* cnt = blockIdx.x ? cnt2 : cnt1;
  unsigned int* start = blockIdx.x ? start2 : start1;
  __shared__ unsigned int part[1024];
  int tid = threadIdx.x;
  int chunk = (n + 1023) >> 10;
  int lo = tid * chunk, hi = min(lo + chunk, n);
  unsigned int s = 0;
  for (int i = lo; i < hi; i++) s += cnt[i];
  part[tid] = s;
  __syncthreads();
  for (int d = 1; d < 1024; d <<= 1) {
    unsigned int t = (tid >= d) ? part[tid - d] : 0u;
    __syncthreads();
    part[tid] += t;
    __syncthreads();
  }
  unsigned int run = part[tid] - s;   // exclusive prefix of this chunk
  for (int i = lo; i < hi; i++) { start[i] = run; run += cnt[i]; }
}

// ---------------- scatter: build sorted-src + position map ------------
__global__ void k_scatter(const int* __restrict__ ei, int E,
                          const int* __restrict__ eib, int EB,
                          const unsigned int* __restrict__ start1, unsigned int* __restrict__ fill1,
                          const unsigned int* __restrict__ start2, unsigned int* __restrict__ fill2,
                          int* __restrict__ ssrc1, int* __restrict__ pos1,
                          int* __restrict__ ssrc2, int* __restrict__ pos2) {
  int idx = blockIdx.x * blockDim.x + threadIdx.x;
  if (idx < E) {
    int d = ei[E + idx];
    unsigned int p = start1[d] + atomicAdd(&fill1[d], 1u);
    ssrc1[p] = ei[idx];
    pos1[idx] = (int)p;
  } else if (idx < E + EB) {
    int e = idx - E;
    int d = eib[EB + e];
    unsigned int p = start2[d] + atomicAdd(&fill2[d], 1u);
    ssrc2[p] = eib[e];
    pos2[e] = (int)p;
  }
}

// ---------------- edge MLP: ea(6)->8->32, write bf16 at SORTED pos ----
__global__ void k_edgemlp(const float* __restrict__ ea,
                          const float* __restrict__ w1, const float* __restrict__ b1,
                          const float* __restrict__ w2, const float* __restrict__ b2,
                          const int* __restrict__ pos,
                          unsigned short* __restrict__ h3s, int ecnt) {
  __shared__ float sw1[KER * 8], sb1[8], sw2[8 * WID], sb2[WID];
  int tid = threadIdx.x;
  if (tid < KER * 8) sw1[tid] = w1[tid];
  if (tid < 8) sb1[tid] = b1[tid];
  if (tid < 8 * WID) sw2[tid] = w2[tid];
  if (tid < WID) sb2[tid] = b2[tid];
  __syncthreads();
  int e = blockIdx.x * blockDim.x + tid;
  if (e >= ecnt) return;
  float a[KER];
  #pragma unroll
  for (int i = 0; i < KER; i++) a[i] = ea[e * KER + i];
  float h8[8];
  #pragma unroll
  for (int o = 0; o < 8; o++) {
    float s = sb1[o];
    #pragma unroll
    for (int i = 0; i < KER; i++) s += a[i] * sw1[i * 8 + o];
    h8[o] = fmaxf(s, 0.f);
  }
  size_t base = (size_t)pos[e] * WID;
  #pragma unroll
  for (int o = 0; o < WID; o++) {
    float s = sb2[o];
    #pragma unroll
    for (int i = 0; i < 8; i++) s += h8[i] * sw2[i * WID + o];
    h3s[base + o] = f2bf(fmaxf(s, 0.f));
  }
}

// ---- pack Wext (w3 rows reindexed kk = kh*32 + i, plus b3 rows) into
// ---- exact B-fragment order: [step s][ntile t][lane l][j], bf16 ------
__global__ void k_pack(const float* __restrict__ w3, const float* __restrict__ b3,
                       unsigned short* __restrict__ outp) {
  int idx = blockIdx.x * blockDim.x + threadIdx.x;
  if (idx >= WEXT_ELEMS) return;
  int j = idx & 7, l = (idx >> 3) & 63, tt = (idx >> 9) & 1, s = idx >> 10;
  int p = ((l >> 4) << 3) + j;        // within-step K position = i (h index)
  int o = tt * 16 + (l & 15);         // output channel
  float v = (s < 32) ? w3[s * 1024 + p * 32 + o] : b3[p * 32 + o];
  outp[idx] = f2bf(v);
}

// ---------------- message kernel: sorted edges, linear I/O, no atomics
// z[e, kk=kh*32+i] = h_src[e][i]*h3[e][kh]; msg = [z ; h_src] @ [Wf ; B3]
__launch_bounds__(512)
__global__ void k_msg(const unsigned short* __restrict__ hbf,
                      const unsigned short* __restrict__ h3s,
                      const int* __restrict__ ssrc, int ecnt,
                      const unsigned short* __restrict__ wext,
                      unsigned short* __restrict__ msgbuf) {
  __shared__ __align__(16) unsigned short wlds[WEXT_ELEMS];   // 67584 B
  {
    const uint4* s4 = (const uint4*)wext;
    uint4* d4 = (uint4*)wlds;
    for (int i = threadIdx.x; i < WEXT_ELEMS / 8; i += blockDim.x) d4[i] = s4[i];
  }
  __syncthreads();
  const int lane = threadIdx.x & 63;
  const int wv = threadIdx.x >> 6;
  const int g = lane >> 4, eo = lane & 15;
  const int ntile = (ecnt + 15) >> 4;
  const int wpb = blockDim.x >> 6;
  const int nwv = gridDim.x * wpb;
  for (int tile = blockIdx.x * wpb + wv; tile < ntile; tile += nwv) {
    const int e = min((tile << 4) + eo, ecnt - 1);
    const int srcn = ssrc[e];
    // full h3 row (32 bf16), linear read in sorted order
    const uint4* h3p = (const uint4*)(h3s + (size_t)e * WID);
    uint4 q0 = h3p[0], q1 = h3p[1], q2 = h3p[2], q3 = h3p[3];
    unsigned int h3w[16];
    h3w[0]=q0.x; h3w[1]=q0.y; h3w[2]=q0.z; h3w[3]=q0.w;
    h3w[4]=q1.x; h3w[5]=q1.y; h3w[6]=q1.z; h3w[7]=q1.w;
    h3w[8]=q2.x; h3w[9]=q2.y; h3w[10]=q2.z; h3w[11]=q2.w;
    h3w[12]=q3.x; h3w[13]=q3.y; h3w[14]=q3.z; h3w[15]=q3.w;
    // h_src fragment: 8 bf16 at positions g*8..g*8+7 (gather, L2-resident)
    uint4 hq = *(const uint4*)(hbf + (size_t)srcn * WID + g * 8);
    bf16x8 hsv = __builtin_bit_cast(bf16x8, hq);
    float hsf[8];
    #pragma unroll
    for (int j = 0; j < 8; j++) hsf[j] = bf2f((unsigned short)hsv[j]);
    f32x4 acc0 = {0.f, 0.f, 0.f, 0.f};
    f32x4 acc1 = {0.f, 0.f, 0.f, 0.f};
    #pragma unroll
    for (int s = 0; s < 32; s++) {
      unsigned int wrd = h3w[s >> 1];
      unsigned short h3b = (s & 1) ? (unsigned short)(wrd >> 16) : (unsigned short)(wrd & 0xffffu);
      float h3f = bf2f(h3b);
      bf16x8 af;
      #pragma unroll
      for (int j = 0; j < 8; j++) af[j] = (short)f2bf(h3f * hsf[j]);
      bf16x8 b0 = *(const bf16x8*)&wlds[((s * 2 + 0) * 64 + lane) * 8];
      bf16x8 b1 = *(const bf16x8*)&wlds[((s * 2 + 1) * 64 + lane) * 8];
      acc0 = __builtin_amdgcn_mfma_f32_16x16x32_bf16(af, b0, acc0, 0, 0, 0);
      acc1 = __builtin_amdgcn_mfma_f32_16x16x32_bf16(af, b1, acc1, 0, 0, 0);
    }
    { // step 32: bias rows, A = raw h_src fragment
      bf16x8 b0 = *(const bf16x8*)&wlds[((32 * 2 + 0) * 64 + lane) * 8];
      bf16x8 b1 = *(const bf16x8*)&wlds[((32 * 2 + 1) * 64 + lane) * 8];
      acc0 = __builtin_amdgcn_mfma_f32_16x16x32_bf16(hsv, b0, acc0, 0, 0, 0);
      acc1 = __builtin_amdgcn_mfma_f32_16x16x32_bf16(hsv, b1, acc1, 0, 0, 0);
    }
    // D layout (m89): col = lane&15 (channel), row = (lane>>4)*4+r (edge slot)
    #pragma unroll
    for (int r = 0; r < 4; r++) {
      int oe = (tile << 4) + g * 4 + r;
      if (oe < ecnt) {
        msgbuf[(size_t)oe * WID + eo]      = f2bf(acc0[r]);
        msgbuf[(size_t)oe * WID + 16 + eo] = f2bf(acc1[r]);
      }
    }
  }
}

// ---- node update: segmented mean over sorted msgs + h@(root)+bias, ReLU
__global__ void k_update(const unsigned short* __restrict__ msg1,
                         const unsigned short* __restrict__ msg2,
                         const unsigned int* __restrict__ start1, const unsigned int* __restrict__ cnt1,
                         const unsigned int* __restrict__ start2, const unsigned int* __restrict__ cnt2,
                         const float* __restrict__ root1, const float* __restrict__ root2,
                         const float* __restrict__ bias1, const float* __restrict__ bias2,
                         float* __restrict__ h, unsigned short* __restrict__ hbf,
                         int last, const float* __restrict__ fc2w, const float* __restrict__ fc2b,
                         float* __restrict__ out, int n_nodes) {
  __shared__ float rs[WID * WID];
  __shared__ float bs[WID];
  __shared__ float hrow[8][WID];
  int tid = threadIdx.x;
  for (int i = tid; i < WID * WID; i += blockDim.x) rs[i] = root1[i] + root2[i];
  if (tid < WID) bs[tid] = bias1[tid] + bias2[tid];
  int o = tid & 31, nl = tid >> 5;
  int n = blockIdx.x * 8 + nl;
  bool ok = (n < n_nodes);
  hrow[nl][o] = ok ? h[(size_t)n * WID + o] : 0.f;
  __syncthreads();
  if (!ok) return;
  unsigned int b1 = start1[n], c1 = cnt1[n];
  unsigned int b2 = start2[n], c2 = cnt2[n];
  float s1 = 0.f, s2 = 0.f;
  for (unsigned int k = 0; k < c1; k++) s1 += bf2f(msg1[(size_t)(b1 + k) * WID + o]);
  for (unsigned int k = 0; k < c2; k++) s2 += bf2f(msg2[(size_t)(b2 + k) * WID + o]);
  float v = s1 / (float)(c1 ? c1 : 1u) + s2 / (float)(c2 ? c2 : 1u) + bs[o];
  #pragma unroll
  for (int i = 0; i < WID; i++) v += hrow[nl][i] * rs[i * WID + o];
  v = fmaxf(v, 0.f);
  h[(size_t)n * WID + o] = v;
  hbf[(size_t)n * WID + o] = f2bf(v);
  if (last) {
    float pv = v * fc2w[o];
    #pragma unroll
    for (int m = 16; m >= 1; m >>= 1) pv += __shfl_xor(pv, m, 32);
    if (o == 0) out[n] = pv + fc2b[0];
  }
}

extern "C" void kernel_launch(void* const* d_in, const int* in_sizes, int n_in,
                              void* d_out, int out_size, void* d_ws, size_t ws_size,
                              hipStream_t stream) {
  const float* x    = (const float*)d_in[0];
  const int*   ei   = (const int*)d_in[1];
  const float* ea   = (const float*)d_in[2];
  const int*   eib  = (const int*)d_in[3];
  const float* eab  = (const float*)d_in[4];
  const float* fc1w = (const float*)d_in[5];
  const float* fc1b = (const float*)d_in[6];
  const float* k1w1 = (const float*)d_in[7];
  const float* k1b1 = (const float*)d_in[8];
  const float* k1w2 = (const float*)d_in[9];
  const float* k1b2 = (const float*)d_in[10];
  const float* k1w3 = (const float*)d_in[11];
  const float* k1b3 = (const float*)d_in[12];
  const float* k2w1 = (const float*)d_in[13];
  const float* k2b1 = (const float*)d_in[14];
  const float* k2w2 = (const float*)d_in[15];
  const float* k2b2 = (const float*)d_in[16];
  const float* k2w3 = (const float*)d_in[17];
  const float* k2b3 = (const float*)d_in[18];
  const float* root1 = (const float*)d_in[19];
  const float* bias1 = (const float*)d_in[20];
  const float* root2 = (const float*)d_in[21];
  const float* bias2 = (const float*)d_in[22];
  const float* fc2w = (const float*)d_in[23];
  const float* fc2b = (const float*)d_in[24];
  float* out = (float*)d_out;

  const int n_nodes = in_sizes[0];
  const int E  = in_sizes[1] / 2;
  const int EB = in_sizes[3] / 2;

  char* ws = (char*)d_ws;
  size_t off = 0;
  auto alloc = [&](size_t bytes) -> void* {
    void* p = ws + off;
    off = (off + bytes + 255) & ~(size_t)255;
    return p;
  };
  unsigned short* h3s1 = (unsigned short*)alloc((size_t)E * WID * 2);
  unsigned short* h3s2 = (unsigned short*)alloc((size_t)EB * WID * 2);
  unsigned short* w1b  = (unsigned short*)alloc((size_t)WEXT_ELEMS * 2);
  unsigned short* w2b  = (unsigned short*)alloc((size_t)WEXT_ELEMS * 2);
  float* h             = (float*)alloc((size_t)n_nodes * WID * 4);
  unsigned short* hbf  = (unsigned short*)alloc((size_t)n_nodes * WID * 2);
  unsigned short* msg1 = (unsigned short*)alloc((size_t)E * WID * 2);
  unsigned short* msg2 = (unsigned short*)alloc((size_t)EB * WID * 2);
  unsigned int* cntblk = (unsigned int*)alloc((size_t)n_nodes * 4 * 4); // cnt1,cnt2,fill1,fill2
  unsigned int* cnt1 = cntblk;
  unsigned int* cnt2 = cntblk + n_nodes;
  unsigned int* fill1 = cntblk + 2 * n_nodes;
  unsigned int* fill2 = cntblk + 3 * n_nodes;
  unsigned int* start1 = (unsigned int*)alloc((size_t)n_nodes * 4);
  unsigned int* start2 = (unsigned int*)alloc((size_t)n_nodes * 4);
  int* ssrc1 = (int*)alloc((size_t)E * 4);
  int* ssrc2 = (int*)alloc((size_t)EB * 4);
  int* pos1  = (int*)alloc((size_t)E * 4);
  int* pos2  = (int*)alloc((size_t)EB * 4);
  (void)ws_size; (void)n_in; (void)out_size;

  // ---- prologue: counting sort of edges by dst (once per call) ----
  hipMemsetAsync(cntblk, 0, (size_t)n_nodes * 4 * 4, stream);
  int tot = E + EB;
  k_cnt<<<(tot + 255) / 256, 256, 0, stream>>>(ei, E, eib, EB, cnt1, cnt2);
  k_scan<<<2, 1024, 0, stream>>>(cnt1, start1, cnt2, start2, n_nodes);
  k_scatter<<<(tot + 255) / 256, 256, 0, stream>>>(ei, E, eib, EB, start1, fill1, start2, fill2,
                                                   ssrc1, pos1, ssrc2, pos2);
  k_h0<<<(n_nodes * WID + 255) / 256, 256, 0, stream>>>(x, fc1w, fc1b, h, hbf, n_nodes);
  k_edgemlp<<<(E + 255) / 256, 256, 0, stream>>>(ea, k1w1, k1b1, k1w2, k1b2, pos1, h3s1, E);
  k_edgemlp<<<(EB + 255) / 256, 256, 0, stream>>>(eab, k2w1, k2b1, k2w2, k2b2, pos2, h3s2, EB);
  k_pack<<<(WEXT_ELEMS + 255) / 256, 256, 0, stream>>>(k1w3, k1b3, w1b);
  k_pack<<<(WEXT_ELEMS + 255) / 256, 256, 0, stream>>>(k2w3, k2b3, w2b);

  for (int t = 0; t < DEPTH; t++) {
    k_msg<<<256, 512, 0, stream>>>(hbf, h3s1, ssrc1, E, w1b, msg1);
    k_msg<<<256, 512, 0, stream>>>(hbf, h3s2, ssrc2, EB, w2b, msg2);
    int last = (t == DEPTH - 1);
    k_update<<<(n_nodes + 7) / 8, 256, 0, stream>>>(msg1, msg2, start1, cnt1, start2, cnt2,
                                                    root1, root2, bias1, bias2, h, hbf,
                                                    last, fc2w, fc2b, out, n_nodes);
  }
}

// Round 5
// 339.831 us; speedup vs baseline: 3.0485x; 2.0059x over previous
//
#include <hip/hip_runtime.h>
#include <hip/hip_bf16.h>

#define WID 32
#define KER 6
#define DEPTH 4
#define WEXT_ELEMS (33 * 2 * 64 * 8)   // steps x ntiles x lanes x 8

typedef __attribute__((ext_vector_type(8))) short bf16x8;
typedef __attribute__((ext_vector_type(4))) float f32x4;

static __device__ __forceinline__ float bf2f(unsigned short u) {
  union { unsigned int u; float f; } v; v.u = ((unsigned int)u) << 16; return v.f;
}
static __device__ __forceinline__ unsigned short f2bf(float f) {
  union { float f; unsigned int u; } v; v.f = f;
  unsigned int r = v.u + 0x7fffu + ((v.u >> 16) & 1u);
  return (unsigned short)(r >> 16);
}

// ---------------- h0 = x @ fc1_w + fc1_b (N,1)@(1,32) -----------------
__global__ void k_h0(const float* __restrict__ x, const float* __restrict__ w,
                     const float* __restrict__ b, float* __restrict__ h,
                     unsigned short* __restrict__ hbf, int n_nodes) {
  int gid = blockIdx.x * blockDim.x + threadIdx.x;
  if (gid >= n_nodes * WID) return;
  int n = gid >> 5, o = gid & 31;
  float v = x[n] * w[o] + b[o];
  h[gid] = v;
  hbf[gid] = f2bf(v);
}

// ------- degree histogram + per-edge rank (both edge sets) ------------
__global__ void k_cnt(const int* __restrict__ ei, int E,
                      const int* __restrict__ eib, int EB,
                      unsigned int* __restrict__ cnt1, unsigned int* __restrict__ cnt2,
                      unsigned int* __restrict__ rank1, unsigned int* __restrict__ rank2) {
  int idx = blockIdx.x * blockDim.x + threadIdx.x;
  if (idx < E) {
    rank1[idx] = atomicAdd(&cnt1[ei[E + idx]], 1u);
  } else if (idx < E + EB) {
    int e = idx - E;
    rank2[e] = atomicAdd(&cnt2[eib[EB + e]], 1u);
  }
}

// ------- scan phase 1: per-block (256) sums over cnt1||cnt2 -----------
__global__ void k_scan1(const unsigned int* __restrict__ cnt, unsigned int* __restrict__ partials,
                        int n2) {
  __shared__ unsigned int s[256];
  int t = threadIdx.x;
  int i = blockIdx.x * 256 + t;
  unsigned int v = (i < n2) ? cnt[i] : 0u;
  s[t] = v;
  __syncthreads();
  for (int d = 128; d > 0; d >>= 1) {
    if (t < d) s[t] += s[t + d];
    __syncthreads();
  }
  if (t == 0) partials[blockIdx.x] = s[0];
}

// ------- scan phase 2: exclusive scan of block partials (1 block) -----
__global__ void k_scan2(unsigned int* __restrict__ partials, int nb) {
  __shared__ unsigned int s[1024];
  int t = threadIdx.x;
  unsigned int v = (t < nb) ? partials[t] : 0u;
  s[t] = v;
  __syncthreads();
  for (int d = 1; d < 1024; d <<= 1) {
    unsigned int u = (t >= d) ? s[t - d] : 0u;
    __syncthreads();
    s[t] += u;
    __syncthreads();
  }
  if (t < nb) partials[t] = s[t] - v;   // exclusive
}

// ------- scan phase 3: block-local exclusive scan + offset ------------
__global__ void k_scan3(const unsigned int* __restrict__ cnt, const unsigned int* __restrict__ partials,
                        unsigned int* __restrict__ start1, unsigned int* __restrict__ start2,
                        int n, int Etot) {
  __shared__ unsigned int s[256];
  int t = threadIdx.x;
  int i = blockIdx.x * 256 + t;
  int n2 = 2 * n;
  unsigned int v = (i < n2) ? cnt[i] : 0u;
  s[t] = v;
  __syncthreads();
  for (int d = 1; d < 256; d <<= 1) {
    unsigned int u = (t >= d) ? s[t - d] : 0u;
    __syncthreads();
    s[t] += u;
    __syncthreads();
  }
  unsigned int ex = s[t] - v + partials[blockIdx.x];
  if (i < n) start1[i] = ex;
  else if (i < n2) start2[i - n] = ex - (unsigned int)Etot;
}

// ---- edge MLP: ea(6)->8->32, fused scatter: write h3s+ssrc at sorted p
__global__ void k_edgemlp(const float* __restrict__ ea,
                          const int* __restrict__ eidx, int ecnt,
                          const unsigned int* __restrict__ rank,
                          const unsigned int* __restrict__ start,
                          const float* __restrict__ w1, const float* __restrict__ b1,
                          const float* __restrict__ w2, const float* __restrict__ b2,
                          unsigned short* __restrict__ h3s, int* __restrict__ ssrc) {
  __shared__ float sw1[KER * 8], sb1[8], sw2[8 * WID], sb2[WID];
  int tid = threadIdx.x;
  if (tid < KER * 8) sw1[tid] = w1[tid];
  if (tid < 8) sb1[tid] = b1[tid];
  if (tid < 8 * WID) sw2[tid] = w2[tid];
  if (tid < WID) sb2[tid] = b2[tid];
  __syncthreads();
  int e = blockIdx.x * blockDim.x + tid;
  if (e >= ecnt) return;
  float a[KER];
  #pragma unroll
  for (int i = 0; i < KER; i++) a[i] = ea[e * KER + i];
  float h8[8];
  #pragma unroll
  for (int o = 0; o < 8; o++) {
    float s = sb1[o];
    #pragma unroll
    for (int i = 0; i < KER; i++) s += a[i] * sw1[i * 8 + o];
    h8[o] = fmaxf(s, 0.f);
  }
  int d = eidx[ecnt + e];
  unsigned int p = start[d] + rank[e];
  ssrc[p] = eidx[e];
  size_t base = (size_t)p * WID;
  #pragma unroll
  for (int o = 0; o < WID; o++) {
    float s = sb2[o];
    #pragma unroll
    for (int i = 0; i < 8; i++) s += h8[i] * sw2[i * WID + o];
    h3s[base + o] = f2bf(fmaxf(s, 0.f));
  }
}

// ---- pack Wext for BOTH kernels into B-fragment order ----------------
__global__ void k_pack2(const float* __restrict__ w3a, const float* __restrict__ b3a,
                        unsigned short* __restrict__ oa,
                        const float* __restrict__ w3b, const float* __restrict__ b3b,
                        unsigned short* __restrict__ ob) {
  int idx = blockIdx.x * blockDim.x + threadIdx.x;
  if (idx >= 2 * WEXT_ELEMS) return;
  int which = idx >= WEXT_ELEMS;
  int id2 = which ? idx - WEXT_ELEMS : idx;
  const float* w3 = which ? w3b : w3a;
  const float* b3 = which ? b3b : b3a;
  unsigned short* outp = which ? ob : oa;
  int j = id2 & 7, l = (id2 >> 3) & 63, tt = (id2 >> 9) & 1, s = id2 >> 10;
  int p = ((l >> 4) << 3) + j;        // within-step K position = i (h index)
  int o = tt * 16 + (l & 15);         // output channel
  float v = (s < 32) ? w3[s * 1024 + p * 32 + o] : b3[p * 32 + o];
  outp[id2] = f2bf(v);
}

// ---- message kernel, BOTH edge sets in one dispatch, no atomics ------
// z[e, kk=kh*32+i] = h_src[e][i]*h3[e][kh]; msg = [z ; h_src] @ [Wf ; B3]
__launch_bounds__(512)
__global__ void k_msg2(const unsigned short* __restrict__ hbf,
                       const unsigned short* __restrict__ h3s1, const int* __restrict__ ssrc1,
                       int ecnt1, const unsigned short* __restrict__ w1,
                       unsigned short* __restrict__ msg1,
                       const unsigned short* __restrict__ h3s2, const int* __restrict__ ssrc2,
                       int ecnt2, const unsigned short* __restrict__ w2,
                       unsigned short* __restrict__ msg2, int B1) {
  const unsigned short* h3s; const int* ssrc; const unsigned short* wext;
  unsigned short* msgbuf; int ecnt, blk0, nblk;
  if ((int)blockIdx.x < B1) {
    h3s = h3s1; ssrc = ssrc1; wext = w1; msgbuf = msg1; ecnt = ecnt1;
    blk0 = blockIdx.x; nblk = B1;
  } else {
    h3s = h3s2; ssrc = ssrc2; wext = w2; msgbuf = msg2; ecnt = ecnt2;
    blk0 = blockIdx.x - B1; nblk = gridDim.x - B1;
  }
  __shared__ __align__(16) unsigned short wlds[WEXT_ELEMS];   // 67584 B
  {
    const uint4* s4 = (const uint4*)wext;
    uint4* d4 = (uint4*)wlds;
    for (int i = threadIdx.x; i < WEXT_ELEMS / 8; i += blockDim.x) d4[i] = s4[i];
  }
  __syncthreads();
  const int lane = threadIdx.x & 63;
  const int wv = threadIdx.x >> 6;
  const int g = lane >> 4, eo = lane & 15;
  const int ntile = (ecnt + 15) >> 4;
  const int wpb = blockDim.x >> 6;
  const int nwv = nblk * wpb;
  for (int tile = blk0 * wpb + wv; tile < ntile; tile += nwv) {
    const int e = min((tile << 4) + eo, ecnt - 1);
    const int srcn = ssrc[e];
    // full h3 row (32 bf16), linear read in sorted order
    const uint4* h3p = (const uint4*)(h3s + (size_t)e * WID);
    uint4 q0 = h3p[0], q1 = h3p[1], q2 = h3p[2], q3 = h3p[3];
    unsigned int h3w[16];
    h3w[0]=q0.x; h3w[1]=q0.y; h3w[2]=q0.z; h3w[3]=q0.w;
    h3w[4]=q1.x; h3w[5]=q1.y; h3w[6]=q1.z; h3w[7]=q1.w;
    h3w[8]=q2.x; h3w[9]=q2.y; h3w[10]=q2.z; h3w[11]=q2.w;
    h3w[12]=q3.x; h3w[13]=q3.y; h3w[14]=q3.z; h3w[15]=q3.w;
    // h_src fragment: 8 bf16 at positions g*8..g*8+7 (gather, L2-resident)
    uint4 hq = *(const uint4*)(hbf + (size_t)srcn * WID + g * 8);
    bf16x8 hsv = __builtin_bit_cast(bf16x8, hq);
    float hsf[8];
    #pragma unroll
    for (int j = 0; j < 8; j++) hsf[j] = bf2f((unsigned short)hsv[j]);
    f32x4 acc0 = {0.f, 0.f, 0.f, 0.f};
    f32x4 acc1 = {0.f, 0.f, 0.f, 0.f};
    #pragma unroll
    for (int s = 0; s < 32; s++) {
      unsigned int wrd = h3w[s >> 1];
      unsigned int fb = (s & 1) ? (wrd & 0xffff0000u) : (wrd << 16);
      float h3f = __builtin_bit_cast(float, fb);
      float p0 = h3f * hsf[0], p1 = h3f * hsf[1], p2 = h3f * hsf[2], p3 = h3f * hsf[3];
      float p4 = h3f * hsf[4], p5 = h3f * hsf[5], p6 = h3f * hsf[6], p7 = h3f * hsf[7];
      uint4 aw;
      asm("v_cvt_pk_bf16_f32 %0, %1, %2" : "=v"(aw.x) : "v"(p0), "v"(p1));
      asm("v_cvt_pk_bf16_f32 %0, %1, %2" : "=v"(aw.y) : "v"(p2), "v"(p3));
      asm("v_cvt_pk_bf16_f32 %0, %1, %2" : "=v"(aw.z) : "v"(p4), "v"(p5));
      asm("v_cvt_pk_bf16_f32 %0, %1, %2" : "=v"(aw.w) : "v"(p6), "v"(p7));
      bf16x8 af = __builtin_bit_cast(bf16x8, aw);
      bf16x8 b0 = *(const bf16x8*)&wlds[((s * 2 + 0) * 64 + lane) * 8];
      bf16x8 b1 = *(const bf16x8*)&wlds[((s * 2 + 1) * 64 + lane) * 8];
      acc0 = __builtin_amdgcn_mfma_f32_16x16x32_bf16(af, b0, acc0, 0, 0, 0);
      acc1 = __builtin_amdgcn_mfma_f32_16x16x32_bf16(af, b1, acc1, 0, 0, 0);
    }
    { // step 32: bias rows, A = raw h_src fragment
      bf16x8 b0 = *(const bf16x8*)&wlds[((32 * 2 + 0) * 64 + lane) * 8];
      bf16x8 b1 = *(const bf16x8*)&wlds[((32 * 2 + 1) * 64 + lane) * 8];
      acc0 = __builtin_amdgcn_mfma_f32_16x16x32_bf16(hsv, b0, acc0, 0, 0, 0);
      acc1 = __builtin_amdgcn_mfma_f32_16x16x32_bf16(hsv, b1, acc1, 0, 0, 0);
    }
    // D layout (m89): col = lane&15 (channel), row = (lane>>4)*4+r (edge slot)
    #pragma unroll
    for (int r = 0; r < 4; r++) {
      int oe = (tile << 4) + g * 4 + r;
      if (oe < ecnt) {
        msgbuf[(size_t)oe * WID + eo]      = f2bf(acc0[r]);
        msgbuf[(size_t)oe * WID + 16 + eo] = f2bf(acc1[r]);
      }
    }
  }
}

// ---- node update: segmented mean over sorted msgs + h@(root)+bias, ReLU
__global__ void k_update(const unsigned short* __restrict__ msg1,
                         const unsigned short* __restrict__ msg2,
                         const unsigned int* __restrict__ start1, const unsigned int* __restrict__ cnt1,
                         const unsigned int* __restrict__ start2, const unsigned int* __restrict__ cnt2,
                         const float* __restrict__ root1, const float* __restrict__ root2,
                         const float* __restrict__ bias1, const float* __restrict__ bias2,
                         float* __restrict__ h, unsigned short* __restrict__ hbf,
                         int last, const float* __restrict__ fc2w, const float* __restrict__ fc2b,
                         float* __restrict__ out, int n_nodes) {
  __shared__ float rs[WID * WID];
  __shared__ float bs[WID];
  __shared__ float hrow[8][WID];
  int tid = threadIdx.x;
  for (int i = tid; i < WID * WID; i += blockDim.x) rs[i] = root1[i] + root2[i];
  if (tid < WID) bs[tid] = bias1[tid] + bias2[tid];
  int o = tid & 31, nl = tid >> 5;
  int n = blockIdx.x * 8 + nl;
  bool ok = (n < n_nodes);
  hrow[nl][o] = ok ? h[(size_t)n * WID + o] : 0.f;
  __syncthreads();
  if (!ok) return;
  unsigned int b1 = start1[n], c1 = cnt1[n];
  unsigned int b2 = start2[n], c2 = cnt2[n];
  float s1 = 0.f, s2 = 0.f;
  for (unsigned int k = 0; k < c1; k++) s1 += bf2f(msg1[(size_t)(b1 + k) * WID + o]);
  for (unsigned int k = 0; k < c2; k++) s2 += bf2f(msg2[(size_t)(b2 + k) * WID + o]);
  float v = s1 / (float)(c1 ? c1 : 1u) + s2 / (float)(c2 ? c2 : 1u) + bs[o];
  #pragma unroll
  for (int i = 0; i < WID; i++) v += hrow[nl][i] * rs[i * WID + o];
  v = fmaxf(v, 0.f);
  h[(size_t)n * WID + o] = v;
  hbf[(size_t)n * WID + o] = f2bf(v);
  if (last) {
    float pv = v * fc2w[o];
    #pragma unroll
    for (int m = 16; m >= 1; m >>= 1) pv += __shfl_xor(pv, m, 32);
    if (o == 0) out[n] = pv + fc2b[0];
  }
}

extern "C" void kernel_launch(void* const* d_in, const int* in_sizes, int n_in,
                              void* d_out, int out_size, void* d_ws, size_t ws_size,
                              hipStream_t stream) {
  const float* x    = (const float*)d_in[0];
  const int*   ei   = (const int*)d_in[1];
  const float* ea   = (const float*)d_in[2];
  const int*   eib  = (const int*)d_in[3];
  const float* eab  = (const float*)d_in[4];
  const float* fc1w = (const float*)d_in[5];
  const float* fc1b = (const float*)d_in[6];
  const float* k1w1 = (const float*)d_in[7];
  const float* k1b1 = (const float*)d_in[8];
  const float* k1w2 = (const float*)d_in[9];
  const float* k1b2 = (const float*)d_in[10];
  const float* k1w3 = (const float*)d_in[11];
  const float* k1b3 = (const float*)d_in[12];
  const float* k2w1 = (const float*)d_in[13];
  const float* k2b1 = (const float*)d_in[14];
  const float* k2w2 = (const float*)d_in[15];
  const float* k2b2 = (const float*)d_in[16];
  const float* k2w3 = (const float*)d_in[17];
  const float* k2b3 = (const float*)d_in[18];
  const float* root1 = (const float*)d_in[19];
  const float* bias1 = (const float*)d_in[20];
  const float* root2 = (const float*)d_in[21];
  const float* bias2 = (const float*)d_in[22];
  const float* fc2w = (const float*)d_in[23];
  const float* fc2b = (const float*)d_in[24];
  float* out = (float*)d_out;

  const int n_nodes = in_sizes[0];
  const int E  = in_sizes[1] / 2;
  const int EB = in_sizes[3] / 2;

  char* ws = (char*)d_ws;
  size_t off = 0;
  auto alloc = [&](size_t bytes) -> void* {
    void* p = ws + off;
    off = (off + bytes + 255) & ~(size_t)255;
    return p;
  };
  unsigned short* h3s1 = (unsigned short*)alloc((size_t)E * WID * 2);
  unsigned short* h3s2 = (unsigned short*)alloc((size_t)EB * WID * 2);
  unsigned short* w1b  = (unsigned short*)alloc((size_t)WEXT_ELEMS * 2);
  unsigned short* w2b  = (unsigned short*)alloc((size_t)WEXT_ELEMS * 2);
  float* h             = (float*)alloc((size_t)n_nodes * WID * 4);
  unsigned short* hbf  = (unsigned short*)alloc((size_t)n_nodes * WID * 2);
  unsigned short* msg1 = (unsigned short*)alloc((size_t)E * WID * 2);
  unsigned short* msg2 = (unsigned short*)alloc((size_t)EB * WID * 2);
  unsigned int* cnt12  = (unsigned int*)alloc((size_t)2 * n_nodes * 4);  // cnt1||cnt2 contiguous
  unsigned int* cnt1 = cnt12;
  unsigned int* cnt2 = cnt12 + n_nodes;
  unsigned int* start1 = (unsigned int*)alloc((size_t)n_nodes * 4);
  unsigned int* start2 = (unsigned int*)alloc((size_t)n_nodes * 4);
  unsigned int* rank1  = (unsigned int*)alloc((size_t)E * 4);
  unsigned int* rank2  = (unsigned int*)alloc((size_t)EB * 4);
  int* ssrc1 = (int*)alloc((size_t)E * 4);
  int* ssrc2 = (int*)alloc((size_t)EB * 4);
  unsigned int* partials = (unsigned int*)alloc((size_t)1024 * 4);
  (void)ws_size; (void)n_in; (void)out_size;

  const int n2 = 2 * n_nodes;
  const int nb = (n2 + 255) / 256;      // scan blocks (391 for N=50000)

  // ---- prologue: counting sort of edges by dst (once per call) ----
  hipMemsetAsync(cnt12, 0, (size_t)n2 * 4, stream);
  int tot = E + EB;
  k_cnt<<<(tot + 255) / 256, 256, 0, stream>>>(ei, E, eib, EB, cnt1, cnt2, rank1, rank2);
  k_scan1<<<nb, 256, 0, stream>>>(cnt12, partials, n2);
  k_scan2<<<1, 1024, 0, stream>>>(partials, nb);
  k_scan3<<<nb, 256, 0, stream>>>(cnt12, partials, start1, start2, n_nodes, E);
  k_h0<<<(n_nodes * WID + 255) / 256, 256, 0, stream>>>(x, fc1w, fc1b, h, hbf, n_nodes);
  k_edgemlp<<<(E + 255) / 256, 256, 0, stream>>>(ea, ei, E, rank1, start1,
                                                 k1w1, k1b1, k1w2, k1b2, h3s1, ssrc1);
  k_edgemlp<<<(EB + 255) / 256, 256, 0, stream>>>(eab, eib, EB, rank2, start2,
                                                  k2w1, k2b1, k2w2, k2b2, h3s2, ssrc2);
  k_pack2<<<(2 * WEXT_ELEMS + 255) / 256, 256, 0, stream>>>(k1w3, k1b3, w1b, k2w3, k2b3, w2b);

  const int GRID = 512;
  int B1 = (int)(((long long)GRID * E) / (E + EB));
  if (B1 < 1) B1 = 1;
  if (B1 > GRID - 1) B1 = GRID - 1;

  for (int t = 0; t < DEPTH; t++) {
    k_msg2<<<GRID, 512, 0, stream>>>(hbf, h3s1, ssrc1, E, w1b, msg1,
                                     h3s2, ssrc2, EB, w2b, msg2, B1);
    int last = (t == DEPTH - 1);
    k_update<<<(n_nodes + 7) / 8, 256, 0, stream>>>(msg1, msg2, start1, cnt1, start2, cnt2,
                                                    root1, root2, bias1, bias2, h, hbf,
                                                    last, fc2w, fc2b, out, n_nodes);
  }
}